// Round 1
// baseline (647.117 us; speedup 1.0000x reference)
//
#include <hip/hip_runtime.h>
#include <hip/hip_bf16.h>
#include <stdint.h>

// Problem constants (from reference)
#define S_LEN   2048
#define BATCH   8
#define NPOS    (BATCH * S_LEN)   // 16384 positions
#define NTAB    16
#define EDIM    64
#define KDIM    (NTAB * EDIM)     // 1024 (GEMM K)
#define NOUT    1024              // n_embd (GEMM N)

typedef float    f32x4_t  __attribute__((ext_vector_type(4)));
typedef __bf16   bf16x8_t __attribute__((ext_vector_type(8)));
typedef unsigned short ushort8_t __attribute__((ext_vector_type(8)));

// ---------- fp32 -> bf16 round-to-nearest-even ----------
__device__ __forceinline__ unsigned short f2bf(float f) {
    uint32_t u = __float_as_uint(f);
    u += 0x7fffu + ((u >> 16) & 1u);
    return (unsigned short)(u >> 16);
}

// ---------- kernel 1: convert out_proj_w fp32 -> bf16 ----------
__global__ __launch_bounds__(256) void wconv_kernel(const float* __restrict__ W,
                                                    unsigned short* __restrict__ Wb) {
    int i = blockIdx.x * 256 + threadIdx.x;            // over 1024*1024/4 float4s
    float4 v = ((const float4*)W)[i];
    ushort4 o;
    o.x = f2bf(v.x); o.y = f2bf(v.y); o.z = f2bf(v.z); o.w = f2bf(v.w);
    ((ushort4*)Wb)[i] = o;
}

// ---------- kernel 2: int64-exact hash -> gather index ----------
__global__ __launch_bounds__(256) void hash_idx_kernel(const int* __restrict__ tok,
                                                       const int* __restrict__ mults,
                                                       const int* __restrict__ bias,
                                                       const int* __restrict__ omask,
                                                       const int* __restrict__ tsize,
                                                       const int* __restrict__ toff,
                                                       int* __restrict__ idx_out) {
    int i = blockIdx.x * 256 + threadIdx.x;            // i < NPOS*NTAB
    int p = i >> 4;                                    // position
    int t = i & 15;                                    // table
    int s = p & (S_LEN - 1);                           // pos within batch row
    uint64_t tk0 = (uint32_t)tok[p];
    uint64_t tk1 = (s >= 1) ? (uint64_t)(uint32_t)tok[p - 1] : 0ull;
    uint64_t tk2 = (s >= 2) ? (uint64_t)(uint32_t)tok[p - 2] : 0ull;
    uint64_t m0 = (uint32_t)mults[t * 3 + 0];
    uint64_t m1 = (uint32_t)mults[t * 3 + 1];
    uint64_t m2 = (uint32_t)mults[t * 3 + 2];
    uint64_t k0v = (uint64_t)(uint32_t)omask[0 * NTAB + t];
    uint64_t k1v = (uint64_t)(uint32_t)omask[1 * NTAB + t];
    uint64_t k2v = (uint64_t)(uint32_t)omask[2 * NTAB + t];
    uint64_t h = (m0 * tk0 * k0v) ^ (m1 * tk1 * k1v) ^ (m2 * tk2 * k2v)
               ^ (uint64_t)(uint32_t)bias[t];
    uint64_t ts = (uint32_t)tsize[t];
    idx_out[i] = (int)(h % ts) + toff[t];
}

// ---------- kernel 3: gather embedding rows, fp32 -> bf16 ----------
// block = one position p; 16 groups of 16 lanes, group t reads table row idx[p,t]
__global__ __launch_bounds__(256) void gather_kernel(const float* __restrict__ table,
                                                     const int* __restrict__ idx,
                                                     unsigned short* __restrict__ emb) {
    int p = blockIdx.x;
    int t = threadIdx.x >> 4;
    int j = threadIdx.x & 15;
    int row = idx[p * NTAB + t];
    float4 v = *(const float4*)(table + (size_t)row * EDIM + j * 4);
    ushort4 o;
    o.x = f2bf(v.x); o.y = f2bf(v.y); o.z = f2bf(v.z); o.w = f2bf(v.w);
    *(ushort4*)(emb + (size_t)p * KDIM + t * EDIM + j * 4) = o;
}

// ---------- kernel 4: bf16 MFMA GEMM, C = A(M x K) * B(N x K)^T ----------
// A = emb [16384 x 1024] bf16, B = Wb [1024 x 1024] bf16 (row n is K-contig)
// 128x128 tile, BK=32, 4 waves each 64x64 acc, global_load_lds width-16 staging.
#define TM 128
#define TN 128
#define BK 32

__global__ __launch_bounds__(256) void gemm_kernel(const unsigned short* __restrict__ A,
                                                   const unsigned short* __restrict__ B,
                                                   float* __restrict__ C) {
    __shared__ __align__(16) unsigned short As[TM * BK];   // 8 KB
    __shared__ __align__(16) unsigned short Bs[TN * BK];   // 8 KB

    const int blk = blockIdx.x;          // 1024 blocks
    const int bm = blk >> 3;             // 0..127
    const int bn = blk & 7;              // 0..7  (XCD-resident W slice)
    const int tid = threadIdx.x;
    const int wave = tid >> 6;
    const int lane = tid & 63;
    const int wm = wave >> 1;            // 0..1
    const int wn = wave & 1;             // 0..1

    const int rsub  = lane >> 2;         // 0..15 : row within 16-row chunk
    const int chunk = lane & 3;          // 0..3  : 8-ushort chunk within row

    f32x4_t acc[4][4] = {};

    const size_t K = (size_t)KDIM;
    const size_t baseAm = (size_t)(bm * TM);
    const size_t baseBn = (size_t)(bn * TN);

    for (int k0 = 0; k0 < KDIM; k0 += BK) {
        // ---- stage A,B tiles: 128 rows x 32 bf16 each via global_load_lds x16B
        #pragma unroll
        for (int c = 0; c < 2; ++c) {
            const int rrel = c * 64 + wave * 16;                 // wave-uniform row base
            const int row  = rrel + rsub;
            const unsigned short* gA = A + (baseAm + row) * K + k0 + chunk * 8;
            const unsigned short* gB = B + (baseBn + row) * K + k0 + chunk * 8;
            unsigned short* lA = &As[rrel * BK];                 // wave-uniform
            unsigned short* lB = &Bs[rrel * BK];
            __builtin_amdgcn_global_load_lds(
                (__attribute__((address_space(1))) void*)gA,
                (__attribute__((address_space(3))) void*)lA, 16, 0, 0);
            __builtin_amdgcn_global_load_lds(
                (__attribute__((address_space(1))) void*)gB,
                (__attribute__((address_space(3))) void*)lB, 16, 0, 0);
        }
        __syncthreads();

        // ---- fragments + 16 MFMA
        const int koff = (lane >> 4) * 8;     // 0,8,16,24
        const int r16  = lane & 15;
        bf16x8_t af[4], bfv[4];
        #pragma unroll
        for (int i = 0; i < 4; ++i) {
            ushort8_t ra = *(const ushort8_t*)&As[(wm * 64 + i * 16 + r16) * BK + koff];
            ushort8_t rb = *(const ushort8_t*)&Bs[(wn * 64 + i * 16 + r16) * BK + koff];
            af[i]  = __builtin_bit_cast(bf16x8_t, ra);
            bfv[i] = __builtin_bit_cast(bf16x8_t, rb);
        }
        #pragma unroll
        for (int i = 0; i < 4; ++i)
            #pragma unroll
            for (int j = 0; j < 4; ++j)
                acc[i][j] = __builtin_amdgcn_mfma_f32_16x16x32_bf16(af[i], bfv[j], acc[i][j], 0, 0, 0);
        __syncthreads();
    }

    // ---- epilogue: C/D layout col = lane&15 (n), row = (lane>>4)*4 + reg (m)
    const int col = lane & 15;
    const int r0  = (lane >> 4) * 4;
    #pragma unroll
    for (int i = 0; i < 4; ++i)
        #pragma unroll
        for (int j = 0; j < 4; ++j)
            #pragma unroll
            for (int r = 0; r < 4; ++r) {
                int m = bm * TM + wm * 64 + i * 16 + r0 + r;
                int n = bn * TN + wn * 64 + j * 16 + col;
                C[(size_t)m * NOUT + n] = acc[i][j][r];
            }
}

extern "C" void kernel_launch(void* const* d_in, const int* in_sizes, int n_in,
                              void* d_out, int out_size, void* d_ws, size_t ws_size,
                              hipStream_t stream) {
    const int*   tok   = (const int*)d_in[0];
    const float* table = (const float*)d_in[1];
    const float* W     = (const float*)d_in[2];
    const int*   mults = (const int*)d_in[3];
    const int*   bias  = (const int*)d_in[4];
    const int*   omask = (const int*)d_in[5];
    const int*   tsize = (const int*)d_in[6];
    const int*   toff  = (const int*)d_in[7];
    float*       out   = (float*)d_out;

    // workspace layout: emb bf16 (32 MB) | Wb bf16 (2 MB) | idx int (1 MB)
    unsigned short* emb = (unsigned short*)d_ws;
    unsigned short* Wb  = (unsigned short*)((char*)d_ws + (size_t)NPOS * KDIM * 2);
    int*            idx = (int*)((char*)d_ws + (size_t)NPOS * KDIM * 2 + (size_t)NOUT * KDIM * 2);

    wconv_kernel<<<(NOUT * KDIM / 4) / 256, 256, 0, stream>>>(W, Wb);
    hash_idx_kernel<<<(NPOS * NTAB) / 256, 256, 0, stream>>>(tok, mults, bias, omask, tsize, toff, idx);
    gather_kernel<<<NPOS, 256, 0, stream>>>(table, idx, emb);
    gemm_kernel<<<1024, 256, 0, stream>>>(emb, Wb, out);
}

// Round 2
// 634.158 us; speedup vs baseline: 1.0204x; 1.0204x over previous
//
#include <hip/hip_runtime.h>
#include <hip/hip_bf16.h>
#include <stdint.h>

// Problem constants (from reference)
#define S_LEN   2048
#define BATCH   8
#define NPOS    (BATCH * S_LEN)   // 16384 positions
#define NTAB    16
#define EDIM    64
#define KDIM    (NTAB * EDIM)     // 1024 (GEMM K)
#define NOUT    1024              // n_embd (GEMM N)

typedef float    f32x4_t  __attribute__((ext_vector_type(4)));
typedef __bf16   bf16x8_t __attribute__((ext_vector_type(8)));
typedef unsigned short ushort8_t __attribute__((ext_vector_type(8)));

// ---------- fp32 -> bf16 round-to-nearest-even ----------
__device__ __forceinline__ unsigned short f2bf(float f) {
    uint32_t u = __float_as_uint(f);
    u += 0x7fffu + ((u >> 16) & 1u);
    return (unsigned short)(u >> 16);
}

// ---------- kernel 1: convert out_proj_w fp32 -> bf16 ----------
__global__ __launch_bounds__(256) void wconv_kernel(const float* __restrict__ W,
                                                    unsigned short* __restrict__ Wb) {
    int i = blockIdx.x * 256 + threadIdx.x;            // over 1024*1024/4 float4s
    float4 v = ((const float4*)W)[i];
    ushort4 o;
    o.x = f2bf(v.x); o.y = f2bf(v.y); o.z = f2bf(v.z); o.w = f2bf(v.w);
    ((ushort4*)Wb)[i] = o;
}

// ---------- kernel 2: int64-exact hash -> gather index ----------
// products < 2^47 and all terms non-negative, so uint64 arithmetic matches
// the reference's int64 semantics exactly (including the % on positive values)
__global__ __launch_bounds__(256) void hash_idx_kernel(const int* __restrict__ tok,
                                                       const int* __restrict__ mults,
                                                       const int* __restrict__ bias,
                                                       const int* __restrict__ omask,
                                                       const int* __restrict__ tsize,
                                                       const int* __restrict__ toff,
                                                       int* __restrict__ idx_out) {
    int i = blockIdx.x * 256 + threadIdx.x;            // i < NPOS*NTAB
    int p = i >> 4;                                    // position
    int t = i & 15;                                    // table
    int s = p & (S_LEN - 1);                           // pos within batch row
    uint64_t tk0 = (uint32_t)tok[p];
    uint64_t tk1 = (s >= 1) ? (uint64_t)(uint32_t)tok[p - 1] : 0ull;
    uint64_t tk2 = (s >= 2) ? (uint64_t)(uint32_t)tok[p - 2] : 0ull;
    uint64_t m0 = (uint32_t)mults[t * 3 + 0];
    uint64_t m1 = (uint32_t)mults[t * 3 + 1];
    uint64_t m2 = (uint32_t)mults[t * 3 + 2];
    uint64_t k0v = (uint64_t)(uint32_t)omask[0 * NTAB + t];
    uint64_t k1v = (uint64_t)(uint32_t)omask[1 * NTAB + t];
    uint64_t k2v = (uint64_t)(uint32_t)omask[2 * NTAB + t];
    uint64_t h = (m0 * tk0 * k0v) ^ (m1 * tk1 * k1v) ^ (m2 * tk2 * k2v)
               ^ (uint64_t)(uint32_t)bias[t];
    uint64_t ts = (uint32_t)tsize[t];
    idx_out[i] = (int)(h % ts) + toff[t];
}

// ---------- kernel 3: gather embedding rows, fp32 -> bf16 ----------
// block = one position p; 16 groups of 16 lanes, group t reads table row idx[p,t]
__global__ __launch_bounds__(256) void gather_kernel(const float* __restrict__ table,
                                                     const int* __restrict__ idx,
                                                     unsigned short* __restrict__ emb) {
    int p = blockIdx.x;
    int t = threadIdx.x >> 4;
    int j = threadIdx.x & 15;
    int row = idx[p * NTAB + t];
    float4 v = *(const float4*)(table + (size_t)row * EDIM + j * 4);
    ushort4 o;
    o.x = f2bf(v.x); o.y = f2bf(v.y); o.z = f2bf(v.z); o.w = f2bf(v.w);
    *(ushort4*)(emb + (size_t)p * KDIM + t * EDIM + j * 4) = o;
}

// ---------- kernel 4: bf16 MFMA GEMM, C = A(M x K) * B(N x K)^T ----------
// A = emb [16384 x 1024] bf16, B = Wb [1024 x 1024] bf16 (row n is K-contig)
// 128x128 tile; 2 sub-buffers of BK=32 staged per barrier round (32 MFMA
// between barriers instead of 16 -> half the vmcnt(0)+barrier drains).
// __launch_bounds__(256,4): cap 128 VGPR -> 4 blocks/CU, no occupancy tail
// (grid = 1024 = exactly 4 * 256 CUs).
#define TM 128
#define TN 128
#define BK 32

__global__ __launch_bounds__(256, 4) void gemm_kernel(const unsigned short* __restrict__ A,
                                                      const unsigned short* __restrict__ B,
                                                      float* __restrict__ C) {
    __shared__ __align__(16) unsigned short As[2][TM * BK];   // 2 x 8 KB
    __shared__ __align__(16) unsigned short Bs[2][TN * BK];   // 2 x 8 KB

    const int blk = blockIdx.x;          // 1024 blocks
    const int bm = blk >> 3;             // 0..127
    const int bn = blk & 7;              // 0..7  (XCD-resident W slice)
    const int tid = threadIdx.x;
    const int wave = tid >> 6;
    const int lane = tid & 63;
    const int wm = wave >> 1;            // 0..1
    const int wn = wave & 1;             // 0..1

    const int rsub  = lane >> 2;         // 0..15 : row within 16-row chunk
    const int chunk = lane & 3;          // 0..3  : 8-ushort chunk within row

    f32x4_t acc[4][4] = {};

    const size_t K = (size_t)KDIM;
    const size_t baseAm = (size_t)(bm * TM);
    const size_t baseBn = (size_t)(bn * TN);

    for (int k0 = 0; k0 < KDIM; k0 += 2 * BK) {
        // ---- stage 2 sub-tiles of A,B: 128 rows x 32 bf16 each, width-16 DMA
        #pragma unroll
        for (int kh = 0; kh < 2; ++kh) {
            #pragma unroll
            for (int c = 0; c < 2; ++c) {
                const int rrel = c * 64 + wave * 16;             // wave-uniform row base
                const int row  = rrel + rsub;
                const unsigned short* gA = A + (baseAm + row) * K + (k0 + kh * BK) + chunk * 8;
                const unsigned short* gB = B + (baseBn + row) * K + (k0 + kh * BK) + chunk * 8;
                unsigned short* lA = &As[kh][rrel * BK];         // wave-uniform
                unsigned short* lB = &Bs[kh][rrel * BK];
                __builtin_amdgcn_global_load_lds(
                    (__attribute__((address_space(1))) void*)gA,
                    (__attribute__((address_space(3))) void*)lA, 16, 0, 0);
                __builtin_amdgcn_global_load_lds(
                    (__attribute__((address_space(1))) void*)gB,
                    (__attribute__((address_space(3))) void*)lB, 16, 0, 0);
            }
        }
        __syncthreads();

        // ---- 2 x 16 MFMA between barriers
        const int koff = (lane >> 4) * 8;     // 0,8,16,24
        const int r16  = lane & 15;
        #pragma unroll
        for (int kh = 0; kh < 2; ++kh) {
            bf16x8_t af[4], bfv[4];
            #pragma unroll
            for (int i = 0; i < 4; ++i) {
                ushort8_t ra = *(const ushort8_t*)&As[kh][(wm * 64 + i * 16 + r16) * BK + koff];
                ushort8_t rb = *(const ushort8_t*)&Bs[kh][(wn * 64 + i * 16 + r16) * BK + koff];
                af[i]  = __builtin_bit_cast(bf16x8_t, ra);
                bfv[i] = __builtin_bit_cast(bf16x8_t, rb);
            }
            #pragma unroll
            for (int i = 0; i < 4; ++i)
                #pragma unroll
                for (int j = 0; j < 4; ++j)
                    acc[i][j] = __builtin_amdgcn_mfma_f32_16x16x32_bf16(af[i], bfv[j], acc[i][j], 0, 0, 0);
        }
        __syncthreads();
    }

    // ---- epilogue: C/D layout col = lane&15 (n), row = (lane>>4)*4 + reg (m)
    const int col = lane & 15;
    const int r0  = (lane >> 4) * 4;
    #pragma unroll
    for (int i = 0; i < 4; ++i)
        #pragma unroll
        for (int j = 0; j < 4; ++j)
            #pragma unroll
            for (int r = 0; r < 4; ++r) {
                int m = bm * TM + wm * 64 + i * 16 + r0 + r;
                int n = bn * TN + wn * 64 + j * 16 + col;
                C[(size_t)m * NOUT + n] = acc[i][j][r];
            }
}

extern "C" void kernel_launch(void* const* d_in, const int* in_sizes, int n_in,
                              void* d_out, int out_size, void* d_ws, size_t ws_size,
                              hipStream_t stream) {
    const int*   tok   = (const int*)d_in[0];
    const float* table = (const float*)d_in[1];
    const float* W     = (const float*)d_in[2];
    const int*   mults = (const int*)d_in[3];
    const int*   bias  = (const int*)d_in[4];
    const int*   omask = (const int*)d_in[5];
    const int*   tsize = (const int*)d_in[6];
    const int*   toff  = (const int*)d_in[7];
    float*       out   = (float*)d_out;

    // workspace layout: emb bf16 (32 MB) | Wb bf16 (2 MB) | idx int (1 MB)
    unsigned short* emb = (unsigned short*)d_ws;
    unsigned short* Wb  = (unsigned short*)((char*)d_ws + (size_t)NPOS * KDIM * 2);
    int*            idx = (int*)((char*)d_ws + (size_t)NPOS * KDIM * 2 + (size_t)NOUT * KDIM * 2);

    wconv_kernel<<<(NOUT * KDIM / 4) / 256, 256, 0, stream>>>(W, Wb);
    hash_idx_kernel<<<(NPOS * NTAB) / 256, 256, 0, stream>>>(tok, mults, bias, omask, tsize, toff, idx);
    gather_kernel<<<NPOS, 256, 0, stream>>>(table, idx, emb);
    gemm_kernel<<<1024, 256, 0, stream>>>(emb, Wb, out);
}